// Round 18
// baseline (990.431 us; speedup 1.0000x reference)
//
#include <hip/hip_runtime.h>
#include <hip/hip_bf16.h>
#include <math.h>

#define NNODE 100000
#define NEDGE 800000
#define DF 128
#define EDIM 32
#define NPB 512           // nodes per bucket
#define NPB_SHIFT 9
#define NBUCK ((NNODE + NPB - 1) / NPB)  // 196
#define EPB 2048          // edges per block in binA
#define SCHUNK 8192       // counts per scan block
#define SBLK ((NNODE + SCHUNK - 1) / SCHUNK)  // 13

typedef __attribute__((ext_vector_type(8))) short short8v;
typedef __attribute__((ext_vector_type(8))) unsigned short ushort8v;
typedef __attribute__((ext_vector_type(4))) float f32x4;
typedef __attribute__((ext_vector_type(2))) float f32x2;
typedef unsigned short u16;

__device__ inline short bf16_of(float x) {
  __hip_bfloat16 h = __float2bfloat16(x);
  return *reinterpret_cast<short*>(&h);
}
__device__ inline float f_of_bf16(u16 u) {
  union { unsigned int i; float f; } c;
  c.i = ((unsigned int)u) << 16;
  return c.f;
}

// ---------------- fused pre-casts ----------------

__global__ void cast2_kernel(const float* __restrict__ a, const float* __restrict__ b,
                             short* __restrict__ ya, short* __restrict__ yb, int n4) {
  int i = blockIdx.x * blockDim.x + threadIdx.x;
  if (i < 2 * n4) {
    const float* s = (i < n4) ? a : b;
    short* y = (i < n4) ? ya : yb;
    int j = (i < n4) ? i : i - n4;
    float4 v = ((const float4*)s)[j];
    short4 o;
    o.x = bf16_of(v.x); o.y = bf16_of(v.y); o.z = bf16_of(v.z); o.w = bf16_of(v.w);
    ((short4*)y)[j] = o;
  }
}

// wt: [kind][mat][h][c] bf16 (transposed); web: [conv][c][h]; webT: [conv][h][c]
__global__ void transW_kernel(const float* __restrict__ Wq, const float* __restrict__ Wk,
                              const float* __restrict__ Wv, const float* __restrict__ Ws,
                              const float* __restrict__ We, short* __restrict__ wt,
                              short* __restrict__ web, short* __restrict__ webT) {
  int i = blockIdx.x * blockDim.x + threadIdx.x;
  if (i < 4 * 4 * 16384) {
    int kind = i >> 16;
    int rem = i & 65535;
    int m = rem >> 14, rr = rem & 16383;
    int c = rr >> 7, h = rr & 127;
    const float* W = kind == 0 ? Wq : kind == 1 ? Wk : kind == 2 ? Wv : Ws;
    wt[(size_t)kind * 65536 + m * 16384 + h * DF + c] =
        bf16_of(W[(size_t)m * 16384 + c * DF + h]);
  } else if (i < 4 * 4 * 16384 + 4 * 4096) {
    int j = i - 4 * 4 * 16384;
    web[j] = bf16_of(We[j]);  // [conv][c][h]
  } else if (i < 4 * 4 * 16384 + 2 * 4 * 4096) {
    int j = i - (4 * 4 * 16384 + 4 * 4096);
    int conv = j >> 12, rr = j & 4095;
    int h = rr >> 5, c = rr & 31;
    webT[j] = bf16_of(We[(size_t)conv * 4096 + c * DF + h]);  // [conv][h][c]
  }
}

// ---------------- CSR build (both edge types fused) ----------------

__global__ void hist2_kernel(const int* __restrict__ d0, const int* __restrict__ d1,
                             int* __restrict__ cnt, int ne) {
  int i = blockIdx.x * blockDim.x + threadIdx.x;
  if (i < 2 * ne) {
    int t = (i >= ne);
    int e = i - t * ne;
    const int* d = t ? d1 : d0;
    atomicAdd(&cnt[t * (NNODE + 1) + d[e]], 1);
  }
}

// ---- 3-phase multi-block exclusive scan of cnt -> off ----

__global__ __launch_bounds__(1024) void scan_sum_kernel(const int* __restrict__ cntg,
                                                        int* __restrict__ bsum, int n) {
  __shared__ int lds[1024];
  int ty = blockIdx.y;
  const int* cnt = cntg + ty * (NNODE + 1);
  int t = threadIdx.x;
  int base = blockIdx.x * SCHUNK;
  int s = 0;
#pragma unroll
  for (int i = 0; i < 8; ++i) {
    int idx = base + t * 8 + i;
    s += (idx < n) ? cnt[idx] : 0;
  }
  lds[t] = s;
  __syncthreads();
#pragma unroll
  for (int st = 512; st > 0; st >>= 1) {
    if (t < st) lds[t] += lds[t + st];
    __syncthreads();
  }
  if (t == 0) bsum[ty * SBLK + blockIdx.x] = lds[0];
}

__global__ void scan_top_kernel(const int* __restrict__ bsum, int* __restrict__ bbase,
                                int* __restrict__ offg, int n) {
  int t = threadIdx.x;
  if (t < 2) {
    int s = 0;
    for (int i = 0; i < SBLK; ++i) {
      bbase[t * SBLK + i] = s;
      s += bsum[t * SBLK + i];
    }
    offg[t * (NNODE + 1) + n] = s;  // total
  }
}

__global__ __launch_bounds__(1024) void scan_local_kernel(const int* __restrict__ cntg,
                                                          const int* __restrict__ bbase,
                                                          int* __restrict__ offg, int n) {
  __shared__ int lds[1024];
  int ty = blockIdx.y;
  const int* cnt = cntg + ty * (NNODE + 1);
  int* off = offg + ty * (NNODE + 1);
  int t = threadIdx.x;
  int base = blockIdx.x * SCHUNK;
  int x[8];
  int s = 0;
#pragma unroll
  for (int i = 0; i < 8; ++i) {
    int idx = base + t * 8 + i;
    x[i] = (idx < n) ? cnt[idx] : 0;
    s += x[i];
  }
  lds[t] = s;
  __syncthreads();
#pragma unroll
  for (int st = 1; st < 1024; st <<= 1) {
    int v2 = (t >= st) ? lds[t - st] : 0;
    __syncthreads();
    lds[t] += v2;
    __syncthreads();
  }
  int excl = bbase[ty * SBLK + blockIdx.x] + lds[t] - s;
#pragma unroll
  for (int i = 0; i < 8; ++i) {
    int idx = base + t * 8 + i;
    if (idx < n) off[idx] = excl;
    excl += x[i];
  }
}

// init per-bucket global cursors from off
__global__ void initcur_kernel(const int* __restrict__ off, int* __restrict__ gcur) {
  int i = blockIdx.x * blockDim.x + threadIdx.x;
  if (i < 2 * NBUCK) {
    int t = (i >= NBUCK);
    int b = i - t * NBUCK;
    gcur[i] = off[t * (NNODE + 1) + b * NPB];
  }
}

// Pass A: bin edges into bucket-major tmp (packed 8B: e<<34 | d<<17 | s)
__global__ __launch_bounds__(256) void binA_kernel(
    const int* __restrict__ s0, const int* __restrict__ d0,
    const int* __restrict__ s1, const int* __restrict__ d1,
    int* __restrict__ gcur, long long* __restrict__ tmp0, long long* __restrict__ tmp1,
    int ne) {
  __shared__ int counts[NBUCK];
  __shared__ int gbase[NBUCK];
  int ty = blockIdx.y;
  const int* ss = ty ? s1 : s0;
  const int* dd = ty ? d1 : d0;
  long long* tmp = ty ? tmp1 : tmp0;
  int t = threadIdx.x;
  for (int i = t; i < NBUCK; i += 256) counts[i] = 0;
  __syncthreads();
  int e0 = blockIdx.x * EPB;
  int bb[8], lp[8], sv[8], dv[8];
#pragma unroll
  for (int i = 0; i < 8; ++i) {
    int e = e0 + i * 256 + t;
    if (e < ne) {
      int d = dd[e];
      sv[i] = ss[e];
      dv[i] = d;
      bb[i] = d >> NPB_SHIFT;
      lp[i] = atomicAdd(&counts[bb[i]], 1);
    } else {
      bb[i] = 0; lp[i] = 0; sv[i] = 0; dv[i] = 0;
    }
  }
  __syncthreads();
  for (int i = t; i < NBUCK; i += 256)
    gbase[i] = counts[i] ? atomicAdd(&gcur[ty * NBUCK + i], counts[i]) : 0;
  __syncthreads();
#pragma unroll
  for (int i = 0; i < 8; ++i) {
    int e = e0 + i * 256 + t;
    if (e < ne) {
      long long rec = ((long long)e << 34) | ((long long)dv[i] << 17) | (unsigned int)sv[i];
      tmp[gbase[bb[i]] + lp[i]] = rec;
    }
  }
}

// Pass B: within-bucket node scatter; writes confined to the bucket's CSR range
__global__ __launch_bounds__(256) void scatB_kernel(
    const long long* __restrict__ tmp0, const long long* __restrict__ tmp1,
    const int* __restrict__ off,
    long long* __restrict__ pair0, long long* __restrict__ pair1) {
  __shared__ int cur[NPB];
  int ty = blockIdx.y;
  const long long* tmp = ty ? tmp1 : tmp0;
  long long* pair = ty ? pair1 : pair0;
  const int* offT = off + ty * (NNODE + 1);
  int b = blockIdx.x;
  int n0 = b * NPB;
  int n1 = (n0 + NPB < NNODE) ? n0 + NPB : NNODE;
  int t = threadIdx.x;
  for (int i = t; i < n1 - n0; i += 256) cur[i] = offT[n0 + i];
  __syncthreads();
  int r0 = offT[n0], r1 = offT[n1];
  for (int j = r0 + t; j < r1; j += 256) {
    long long rec = tmp[j];
    int s = (int)(rec & 0x1FFFF);
    int d = (int)((rec >> 17) & 0x1FFFF);
    int e = (int)(rec >> 34);
    int p = atomicAdd(&cur[d - n0], 1);
    pair[p] = (unsigned int)s | ((long long)e << 32);
  }
}

// gather-permute: random line-exact ea reads, coalesced bf16 eac writes
__global__ __launch_bounds__(256) void permute_ea_kernel(
    const float* __restrict__ ea0, const long long* __restrict__ pair0,
    u16* __restrict__ eac0,
    const float* __restrict__ ea1, const long long* __restrict__ pair1,
    u16* __restrict__ eac1, int ne) {
  int gid = blockIdx.x * 256 + threadIdx.x;  // 4 threads per CSR slot
  int tot = ne * 4;
  if (gid >= 2 * tot) return;
  int ty = (gid >= tot);
  int g = gid - ty * tot;
  int j = g >> 2, part = g & 3;
  const long long* pair = ty ? pair1 : pair0;
  const float* ea = ty ? ea1 : ea0;
  u16* eac = ty ? eac1 : eac0;
  int e = (int)(pair[j] >> 32);
  const float4* r = (const float4*)(ea + (size_t)e * EDIM + part * 8);
  float4 a = r[0], b = r[1];
  short8v s;
  s[0] = bf16_of(a.x); s[1] = bf16_of(a.y); s[2] = bf16_of(a.z); s[3] = bf16_of(a.w);
  s[4] = bf16_of(b.x); s[5] = bf16_of(b.y); s[6] = bf16_of(b.z); s[7] = bf16_of(b.w);
  *(short8v*)(eac + (size_t)j * EDIM + part * 8) = s;
}

// ---------------- fused MFMA projections: q(+gq),k,v in one dispatch ----------------
// job0: q GEMM then gq = web @ q via LDS-staged q tile; job1: k,v into kvb rows of 256
__global__ __launch_bounds__(256) void proj_kernel(
    const short* __restrict__ xd, const short* __restrict__ xs, int n,
    const short* __restrict__ wtq, const float* __restrict__ bq, short* __restrict__ qb,
    const short* __restrict__ wtk, const float* __restrict__ bk,
    const short* __restrict__ wtv, const float* __restrict__ bv, short* __restrict__ kvb,
    const short* __restrict__ web, float* __restrict__ gq) {
  __shared__ short Xs[128 * 128];
  int t = threadIdx.x;
  int row0 = blockIdx.x * 128;
  int job = blockIdx.y;
  const short* X = job ? xs : xd;

#pragma unroll
  for (int i = 0; i < 8; ++i) {
    int idx8 = t + i * 256;
    int row = idx8 >> 4;
    int q8 = idx8 & 15;
    short8v val = (short8v){0, 0, 0, 0, 0, 0, 0, 0};
    if (row0 + row < n) val = ((const short8v*)(X + (size_t)(row0 + row) * DF))[q8];
    *(short8v*)&Xs[row * 128 + ((q8 ^ (row & 15)) << 3)] = val;
  }
  __syncthreads();

  int lane = t & 63, wave = t >> 6;
  int wm = wave >> 1, wh = wave & 1;
  int fr = lane & 15, kq = lane >> 4;
  int pmax = job ? 2 : 1;

  for (int p = 0; p < pmax; ++p) {
    const short* Wt = job ? (p ? wtv : wtk) : wtq;
    const float* bb = job ? (p ? bv : bk) : bq;
    f32x4 acc[4][4];
#pragma unroll
    for (int m = 0; m < 4; ++m)
#pragma unroll
      for (int nf = 0; nf < 4; ++nf) acc[m][nf] = (f32x4){0.f, 0.f, 0.f, 0.f};

#pragma unroll
    for (int kk = 0; kk < 4; ++kk) {
      short8v xf[4], wf[4];
      int chunk = kk * 4 + kq;
#pragma unroll
      for (int m = 0; m < 4; ++m) {
        int row = wm * 64 + m * 16 + fr;
        xf[m] = *(const short8v*)&Xs[row * 128 + ((chunk ^ (row & 15)) << 3)];
      }
#pragma unroll
      for (int nf = 0; nf < 4; ++nf) {
        int h = wh * 64 + nf * 16 + fr;
        wf[nf] = *(const short8v*)(Wt + (size_t)h * DF + kk * 32 + kq * 8);
      }
#pragma unroll
      for (int m = 0; m < 4; ++m)
#pragma unroll
        for (int nf = 0; nf < 4; ++nf)
          acc[m][nf] = __builtin_amdgcn_mfma_f32_16x16x32_bf16(wf[nf], xf[m], acc[m][nf], 0, 0, 0);
    }

    if (!job) __syncthreads();  // all waves done reading Xs before q-tile overwrite

#pragma unroll
    for (int nf = 0; nf < 4; ++nf) {
      float4 b4 = *(const float4*)(bb + wh * 64 + nf * 16 + kq * 4);
#pragma unroll
      for (int m = 0; m < 4; ++m) {
        int node = row0 + wm * 64 + m * 16 + fr;
        f32x4 r = acc[m][nf];
        int col = wh * 64 + nf * 16 + kq * 4;
        short4 s4;
        s4.x = bf16_of(r[0] + b4.x);
        s4.y = bf16_of(r[1] + b4.y);
        s4.z = bf16_of(r[2] + b4.z);
        s4.w = bf16_of(r[3] + b4.w);
        if (node < n) {
          if (job) {
            *(short4*)(kvb + (size_t)node * 256 + p * 128 + col) = s4;
          } else {
            *(short4*)(qb + (size_t)node * DF + col) = s4;
          }
        }
        if (!job) {
          // stage q tile in LDS (swizzled): row = local node, chunk = col>>3
          int lrow = wm * 64 + m * 16 + fr;
          int chunk = col >> 3, within = col & 7;
          *(short4*)&Xs[lrow * 128 + ((chunk ^ (lrow & 15)) << 3) + within] = s4;
        }
      }
    }

    if (!job) {
      __syncthreads();
      // gq = web @ q : wave handles nodes wave*32..+32, all 32 c
      int nrow0 = wave * 32;
      f32x4 gacc[2][2];
#pragma unroll
      for (int mm = 0; mm < 2; ++mm)
#pragma unroll
        for (int nf = 0; nf < 2; ++nf) gacc[mm][nf] = (f32x4){0.f, 0.f, 0.f, 0.f};
#pragma unroll
      for (int kk = 0; kk < 4; ++kk) {
        short8v af[2], bfr[2];
#pragma unroll
        for (int nf = 0; nf < 2; ++nf) {
          int cc = nf * 16 + fr;
          af[nf] = *(const short8v*)(web + (size_t)cc * DF + kk * 32 + kq * 8);
        }
        int chunk = kk * 4 + kq;
#pragma unroll
        for (int mm = 0; mm < 2; ++mm) {
          int lrow = nrow0 + mm * 16 + fr;
          bfr[mm] = *(const short8v*)&Xs[lrow * 128 + ((chunk ^ (lrow & 15)) << 3)];
        }
#pragma unroll
        for (int mm = 0; mm < 2; ++mm)
#pragma unroll
          for (int nf = 0; nf < 2; ++nf)
            gacc[mm][nf] = __builtin_amdgcn_mfma_f32_16x16x32_bf16(af[nf], bfr[mm], gacc[mm][nf], 0, 0, 0);
      }
#pragma unroll
      for (int mm = 0; mm < 2; ++mm) {
        int node = row0 + nrow0 + mm * 16 + fr;
        if (node < n) {
#pragma unroll
          for (int nf = 0; nf < 2; ++nf)
            *(f32x4*)(gq + (size_t)node * 32 + nf * 16 + kq * 4) = gacc[mm][nf];
        }
      }
    }
  }
}

// ---------------- fused edge attention: 1 node per 16-lane group, 4 edges/iter ----------------
// read-once streams (q, gq, pairs, eac) use nontemporal loads so the kv gather
// table stays L3-resident; kv loads remain cached.
template <int PERM>
__global__ __launch_bounds__(256) void edge_attn_kernel(
    const short* __restrict__ qb, const short* __restrict__ kvb,
    const float* __restrict__ gq, const float* __restrict__ be,
    const long long* __restrict__ pairs, const int* __restrict__ off,
    const u16* __restrict__ eac, const float* __restrict__ ea,
    short* __restrict__ tmpob, short* __restrict__ accb, int nd) {
  int lane = threadIdx.x & 63;
  int grp = lane >> 4, sl = lane & 15;
  int node = blockIdx.x * 16 + (threadIdx.x >> 6) * 4 + grp;
  if (node >= nd) return;
  int e0 = off[node], e1 = off[node + 1];

  // lane owns dims sl*8..+8 of its group's node
  ushort8v qu = __builtin_nontemporal_load(
      (const ushort8v*)((const u16*)qb + (size_t)node * DF + sl * 8));
  float qd[8];
#pragma unroll
  for (int d = 0; d < 8; ++d) qd[d] = f_of_bf16(qu[d]);
  float bed[8];
  {
    float4 b0 = *(const float4*)(be + sl * 8);
    float4 b1 = *(const float4*)(be + sl * 8 + 4);
    bed[0] = b0.x; bed[1] = b0.y; bed[2] = b0.z; bed[3] = b0.w;
    bed[4] = b1.x; bed[5] = b1.y; bed[6] = b1.z; bed[7] = b1.w;
  }
  float pb = 0.f;
#pragma unroll
  for (int d = 0; d < 8; ++d) pb += qd[d] * bed[d];
#pragma unroll
  for (int o = 1; o <= 8; o <<= 1) pb += __shfl_xor(pb, o);

  f32x2 gq2 = __builtin_nontemporal_load((const f32x2*)(gq + (size_t)node * 32 + sl * 2));

  const float scale = 0.08838834764831845f;  // 128^-0.5
  float m = -INFINITY, ssum = 0.f, an0 = 0.f, an1 = 0.f;
  float agg[8];
#pragma unroll
  for (int d = 0; d < 8; ++d) agg[d] = 0.f;

  for (int j0 = e0; j0 < e1; j0 += 4) {
    int jc[4], si[4];
    float eax[4], eay[4], p[4], a[4];
    ushort8v kv[4], vv[4];
#pragma unroll
    for (int i = 0; i < 4; ++i) {
      int j = j0 + i;
      jc[i] = (j < e1) ? j : e1 - 1;
    }
    long long pr[4];
#pragma unroll
    for (int i = 0; i < 4; ++i) pr[i] = __builtin_nontemporal_load(&pairs[jc[i]]);
#pragma unroll
    for (int i = 0; i < 4; ++i) si[i] = (int)(unsigned int)pr[i];
#pragma unroll
    for (int i = 0; i < 4; ++i) {
      if (PERM) {
        unsigned int u = __builtin_nontemporal_load(
            (const unsigned int*)(eac + (size_t)jc[i] * EDIM + sl * 2));
        eax[i] = f_of_bf16((u16)(u & 0xFFFF));
        eay[i] = f_of_bf16((u16)(u >> 16));
      } else {
        int e = (int)(pr[i] >> 32);
        float2 f = *(const float2*)(ea + (size_t)e * EDIM + sl * 2);
        eax[i] = f.x; eay[i] = f.y;
      }
    }
#pragma unroll
    for (int i = 0; i < 4; ++i) {
      const u16* kvp = (const u16*)kvb + (size_t)si[i] * 256 + sl * 8;
      kv[i] = *(const ushort8v*)kvp;
      vv[i] = *(const ushort8v*)(kvp + 128);
    }
#pragma unroll
    for (int i = 0; i < 4; ++i) {
      p[i] = eax[i] * gq2[0] + eay[i] * gq2[1];
#pragma unroll
      for (int d = 0; d < 8; ++d) p[i] += qd[d] * f_of_bf16(kv[i][d]);
    }
#pragma unroll
    for (int o = 1; o <= 8; o <<= 1) {
#pragma unroll
      for (int i = 0; i < 4; ++i) p[i] += __shfl_xor(p[i], o);
    }
#pragma unroll
    for (int i = 0; i < 4; ++i)
      a[i] = (j0 + i < e1) ? (p[i] + pb) * scale : -INFINITY;
    float mn = fmaxf(fmaxf(m, fmaxf(a[0], a[1])), fmaxf(a[2], a[3]));
    if (mn > m) {  // group-uniform
      float f = __expf(m - mn);
      ssum *= f; an0 *= f; an1 *= f;
#pragma unroll
      for (int d = 0; d < 8; ++d) agg[d] *= f;
      m = mn;
    }
#pragma unroll
    for (int i = 0; i < 4; ++i) {
      float w = __expf(a[i] - m);  // 0 for invalid (a = -inf)
      ssum += w;
      an0 += w * eax[i];
      an1 += w * eay[i];
#pragma unroll
      for (int d = 0; d < 8; ++d) agg[d] += w * f_of_bf16(vv[i][d]);
    }
  }

  float inv = (ssum > 0.f) ? 1.f / ssum : 0.f;
  short2 a2;
  a2.x = bf16_of(an0 * inv);
  a2.y = bf16_of(an1 * inv);
  *(short2*)(accb + (size_t)node * 32 + sl * 2) = a2;
  short8v t8;
#pragma unroll
  for (int d = 0; d < 8; ++d)
    t8[d] = bf16_of((ssum > 0.f) ? agg[d] * inv + bed[d] : 0.f);
  *(short8v*)(tmpob + (size_t)node * DF + sl * 8) = t8;
}

// ---------------- fused epilogue: out = [relu](xd@Ws + bs + tmpob + accb @ We) ----------------
__global__ __launch_bounds__(256) void skip_accw_kernel(
    const short* __restrict__ xd, int n,
    const short* __restrict__ wts, const float* __restrict__ bs,
    const short* __restrict__ tmpob, const short* __restrict__ accb,
    const short* __restrict__ webT,
    float* __restrict__ outf, short* __restrict__ outb, int relu) {
  __shared__ short Xs[128 * 128];
  int t = threadIdx.x;
  int row0 = blockIdx.x * 128;

#pragma unroll
  for (int i = 0; i < 8; ++i) {
    int idx8 = t + i * 256;
    int row = idx8 >> 4;
    int q8 = idx8 & 15;
    short8v val = (short8v){0, 0, 0, 0, 0, 0, 0, 0};
    if (row0 + row < n) val = ((const short8v*)(xd + (size_t)(row0 + row) * DF))[q8];
    *(short8v*)&Xs[row * 128 + ((q8 ^ (row & 15)) << 3)] = val;
  }
  __syncthreads();

  int lane = t & 63, wave = t >> 6;
  int wm = wave >> 1, wh = wave & 1;
  int fr = lane & 15, kq = lane >> 4;

  f32x4 acc[4][4];
#pragma unroll
  for (int m = 0; m < 4; ++m)
#pragma unroll
    for (int nf = 0; nf < 4; ++nf) acc[m][nf] = (f32x4){0.f, 0.f, 0.f, 0.f};

  // skip GEMM: xd @ Ws (same fragment pattern as proj)
#pragma unroll
  for (int kk = 0; kk < 4; ++kk) {
    short8v xf[4], wf[4];
    int chunk = kk * 4 + kq;
#pragma unroll
    for (int m = 0; m < 4; ++m) {
      int row = wm * 64 + m * 16 + fr;
      xf[m] = *(const short8v*)&Xs[row * 128 + ((chunk ^ (row & 15)) << 3)];
    }
#pragma unroll
    for (int nf = 0; nf < 4; ++nf) {
      int h = wh * 64 + nf * 16 + fr;
      wf[nf] = *(const short8v*)(wts + (size_t)h * DF + kk * 32 + kq * 8);
    }
#pragma unroll
    for (int m = 0; m < 4; ++m)
#pragma unroll
      for (int nf = 0; nf < 4; ++nf)
        acc[m][nf] = __builtin_amdgcn_mfma_f32_16x16x32_bf16(wf[nf], xf[m], acc[m][nf], 0, 0, 0);
  }

  // ee GEMM: accb @ We^T fragments (K=32, one MFMA per (m,nf)), accumulated into acc
  {
    short8v af[4], bm[4];
#pragma unroll
    for (int nf = 0; nf < 4; ++nf) {
      int h = wh * 64 + nf * 16 + fr;
      af[nf] = *(const short8v*)(webT + (size_t)h * 32 + kq * 8);
    }
#pragma unroll
    for (int m = 0; m < 4; ++m) {
      int row = row0 + wm * 64 + m * 16 + fr;
      int rc = (row < n) ? row : n - 1;
      bm[m] = *(const short8v*)(accb + (size_t)rc * 32 + kq * 8);
    }
#pragma unroll
    for (int m = 0; m < 4; ++m)
#pragma unroll
      for (int nf = 0; nf < 4; ++nf)
        acc[m][nf] = __builtin_amdgcn_mfma_f32_16x16x32_bf16(af[nf], bm[m], acc[m][nf], 0, 0, 0);
  }

#pragma unroll
  for (int nf = 0; nf < 4; ++nf) {
    float4 b4 = *(const float4*)(bs + wh * 64 + nf * 16 + kq * 4);
#pragma unroll
    for (int m = 0; m < 4; ++m) {
      int node = row0 + wm * 64 + m * 16 + fr;
      if (node < n) {
        int col = wh * 64 + nf * 16 + kq * 4;
        size_t o = (size_t)node * DF + col;
        ushort4 tb = *(const ushort4*)((const u16*)tmpob + o);
        f32x4 r = acc[m][nf];
        float r0 = r[0] + b4.x + f_of_bf16(tb.x);
        float r1 = r[1] + b4.y + f_of_bf16(tb.y);
        float r2 = r[2] + b4.z + f_of_bf16(tb.z);
        float r3 = r[3] + b4.w + f_of_bf16(tb.w);
        if (relu) {
          r0 = fmaxf(r0, 0.f); r1 = fmaxf(r1, 0.f);
          r2 = fmaxf(r2, 0.f); r3 = fmaxf(r3, 0.f);
        }
        if (outf) *(float4*)(outf + o) = make_float4(r0, r1, r2, r3);
        if (outb) {
          short4 s4;
          s4.x = bf16_of(r0); s4.y = bf16_of(r1); s4.z = bf16_of(r2); s4.w = bf16_of(r3);
          *(short4*)(outb + o) = s4;
        }
      }
    }
  }
}

// ---------------- launch ----------------

extern "C" void kernel_launch(void* const* d_in, const int* in_sizes, int n_in,
                              void* d_out, int out_size, void* d_ws, size_t ws_size,
                              hipStream_t stream) {
  const float* x_user = (const float*)d_in[0];
  const float* x_item = (const float*)d_in[1];
  const float* ea_ui = (const float*)d_in[2];
  const float* ea_iu = (const float*)d_in[3];
  const float* Wq = (const float*)d_in[4];
  const float* bq = (const float*)d_in[5];
  const float* Wk = (const float*)d_in[6];
  const float* bk = (const float*)d_in[7];
  const float* Wv = (const float*)d_in[8];
  const float* bv = (const float*)d_in[9];
  const float* We = (const float*)d_in[10];
  const float* be = (const float*)d_in[11];
  const float* Ws = (const float*)d_in[12];
  const float* bs = (const float*)d_in[13];
  const int* ei_ui = (const int*)d_in[14];
  const int* ei_iu = (const int*)d_in[15];
  float* out = (float*)d_out;

  char* wp = (char*)d_ws;
  size_t used = 0;
  auto alloc = [&](size_t bytes) {
    void* p = (void*)(wp + used);
    used += (bytes + 255) & ~(size_t)255;
    return p;
  };
  const size_t NB = (size_t)NNODE * DF;
  short* xub = (short*)alloc(NB * 2);
  short* xib = (short*)alloc(NB * 2);
  short* xu1b = (short*)alloc(NB * 2);
  short* xi1b = (short*)alloc(NB * 2);
  short* qb = (short*)alloc(NB * 2);
  short* kvb = (short*)alloc(NB * 4);   // interleaved k|v rows of 256
  short* tmpob = (short*)alloc(NB * 2);
  float* gqbuf = (float*)alloc((size_t)NNODE * 32 * 4);
  short* accb = (short*)alloc((size_t)NNODE * 32 * 2);
  short* wt = (short*)alloc((size_t)4 * 4 * 16384 * 2);
  short* web = (short*)alloc((size_t)4 * 4096 * 2);
  short* webT = (short*)alloc((size_t)4 * 4096 * 2);
  int* cnt = (int*)alloc((size_t)2 * (NNODE + 1) * 4);
  int* off = (int*)alloc((size_t)2 * (NNODE + 1) * 4);
  int* bsum = (int*)alloc((size_t)2 * SBLK * 4);
  int* bbase = (int*)alloc((size_t)2 * SBLK * 4);
  int* gcur = (int*)alloc((size_t)2 * NBUCK * 4);
  long long* tmp_ui = (long long*)alloc((size_t)NEDGE * 8);
  long long* tmp_iu = (long long*)alloc((size_t)NEDGE * 8);
  long long* pair_ui = (long long*)alloc((size_t)NEDGE * 8);
  long long* pair_iu = (long long*)alloc((size_t)NEDGE * 8);
  size_t eac_bytes = (size_t)NEDGE * EDIM * 2;
  bool use_eac = (used + 2 * (eac_bytes + 256)) <= ws_size;
  u16* eac_ui = use_eac ? (u16*)alloc(eac_bytes) : nullptr;
  u16* eac_iu = use_eac ? (u16*)alloc(eac_bytes) : nullptr;

  const int PB = (NNODE + 127) / 128;  // 782
  int* off_ui = off;
  int* off_iu = off + (NNODE + 1);

  cast2_kernel<<<(int)(2 * NB / 4 + 255) / 256, 256, 0, stream>>>(
      x_user, x_item, xub, xib, (int)(NB / 4));
  transW_kernel<<<(4 * 4 * 16384 + 2 * 4 * 4096 + 255) / 256, 256, 0, stream>>>(
      Wq, Wk, Wv, Ws, We, wt, web, webT);

  hipMemsetAsync(cnt, 0, 2 * (NNODE + 1) * sizeof(int), stream);
  hist2_kernel<<<(2 * NEDGE + 255) / 256, 256, 0, stream>>>(
      ei_ui + NEDGE, ei_iu + NEDGE, cnt, NEDGE);
  {
    dim3 gs(SBLK, 2);
    scan_sum_kernel<<<gs, 1024, 0, stream>>>(cnt, bsum, NNODE);
    scan_top_kernel<<<1, 64, 0, stream>>>(bsum, bbase, off, NNODE);
    scan_local_kernel<<<gs, 1024, 0, stream>>>(cnt, bbase, off, NNODE);
  }
  initcur_kernel<<<(2 * NBUCK + 255) / 256, 256, 0, stream>>>(off, gcur);
  {
    dim3 gA((NEDGE + EPB - 1) / EPB, 2);
    binA_kernel<<<gA, 256, 0, stream>>>(
        ei_ui, ei_ui + NEDGE, ei_iu, ei_iu + NEDGE, gcur, tmp_ui, tmp_iu, NEDGE);
    dim3 gB(NBUCK, 2);
    scatB_kernel<<<gB, 256, 0, stream>>>(tmp_ui, tmp_iu, off, pair_ui, pair_iu);
  }
  if (use_eac)
    permute_ea_kernel<<<(2 * NEDGE * 4 + 255) / 256, 256, 0, stream>>>(
        ea_ui, pair_ui, eac_ui, ea_iu, pair_iu, eac_iu, NEDGE);

  auto run_conv = [&](const short* xsb, const short* xdb, int wsel, const u16* eac_t,
                      const float* ea_t, const long long* pair_t,
                      const int* off_t, float* outfp, short* outbp, int relu) {
    dim3 g(PB, 2);
    proj_kernel<<<g, 256, 0, stream>>>(
        xdb, xsb, NNODE,
        wt + (size_t)0 * 65536 + (size_t)wsel * 16384, bq + (size_t)wsel * DF, qb,
        wt + (size_t)1 * 65536 + (size_t)wsel * 16384, bk + (size_t)wsel * DF,
        wt + (size_t)2 * 65536 + (size_t)wsel * 16384, bv + (size_t)wsel * DF, kvb,
        web + (size_t)wsel * 4096, gqbuf);
    if (use_eac)
      edge_attn_kernel<1><<<(NNODE + 15) / 16, 256, 0, stream>>>(
          qb, kvb, gqbuf, be + (size_t)wsel * DF,
          pair_t, off_t, eac_t, nullptr, tmpob, accb, NNODE);
    else
      edge_attn_kernel<0><<<(NNODE + 15) / 16, 256, 0, stream>>>(
          qb, kvb, gqbuf, be + (size_t)wsel * DF,
          pair_t, off_t, nullptr, ea_t, tmpob, accb, NNODE);
    skip_accw_kernel<<<PB, 256, 0, stream>>>(
        xdb, NNODE, wt + (size_t)3 * 65536 + (size_t)wsel * 16384, bs + (size_t)wsel * DF,
        tmpob, accb, webT + (size_t)wsel * 4096, outfp, outbp, relu);
  };

  // layer 0 (ReLU): outputs bf16 only
  run_conv(xub, xib, 0, eac_ui, ea_ui, pair_ui, off_ui, nullptr, xi1b, 1);
  run_conv(xib, xub, 1, eac_iu, ea_iu, pair_iu, off_iu, nullptr, xu1b, 1);
  // layer 1 (no ReLU): f32 into d_out = [x_user | x_item]
  run_conv(xu1b, xi1b, 2, eac_ui, ea_ui, pair_ui, off_ui, out + NB, nullptr, 0);
  run_conv(xi1b, xu1b, 3, eac_iu, ea_iu, pair_iu, off_iu, out, nullptr, 0);
}

// Round 19
// 964.100 us; speedup vs baseline: 1.0273x; 1.0273x over previous
//
#include <hip/hip_runtime.h>
#include <hip/hip_bf16.h>
#include <math.h>

#define NNODE 100000
#define NEDGE 800000
#define DF 128
#define EDIM 32
#define NPB 512           // nodes per bucket
#define NPB_SHIFT 9
#define NBUCK ((NNODE + NPB - 1) / NPB)  // 196
#define EPB 2048          // edges per block in binA
#define SCHUNK 8192       // counts per scan block
#define SBLK ((NNODE + SCHUNK - 1) / SCHUNK)  // 13

typedef __attribute__((ext_vector_type(8))) short short8v;
typedef __attribute__((ext_vector_type(8))) unsigned short ushort8v;
typedef __attribute__((ext_vector_type(4))) float f32x4;
typedef unsigned short u16;

__device__ inline short bf16_of(float x) {
  __hip_bfloat16 h = __float2bfloat16(x);
  return *reinterpret_cast<short*>(&h);
}
__device__ inline float f_of_bf16(u16 u) {
  union { unsigned int i; float f; } c;
  c.i = ((unsigned int)u) << 16;
  return c.f;
}

// ---------------- fused pre-casts ----------------

__global__ void cast2_kernel(const float* __restrict__ a, const float* __restrict__ b,
                             short* __restrict__ ya, short* __restrict__ yb, int n4) {
  int i = blockIdx.x * blockDim.x + threadIdx.x;
  if (i < 2 * n4) {
    const float* s = (i < n4) ? a : b;
    short* y = (i < n4) ? ya : yb;
    int j = (i < n4) ? i : i - n4;
    float4 v = ((const float4*)s)[j];
    short4 o;
    o.x = bf16_of(v.x); o.y = bf16_of(v.y); o.z = bf16_of(v.z); o.w = bf16_of(v.w);
    ((short4*)y)[j] = o;
  }
}

// wt: [kind][mat][h][c] bf16 (transposed); web: [conv][c][h]; webT: [conv][h][c]
__global__ void transW_kernel(const float* __restrict__ Wq, const float* __restrict__ Wk,
                              const float* __restrict__ Wv, const float* __restrict__ Ws,
                              const float* __restrict__ We, short* __restrict__ wt,
                              short* __restrict__ web, short* __restrict__ webT) {
  int i = blockIdx.x * blockDim.x + threadIdx.x;
  if (i < 4 * 4 * 16384) {
    int kind = i >> 16;
    int rem = i & 65535;
    int m = rem >> 14, rr = rem & 16383;
    int c = rr >> 7, h = rr & 127;
    const float* W = kind == 0 ? Wq : kind == 1 ? Wk : kind == 2 ? Wv : Ws;
    wt[(size_t)kind * 65536 + m * 16384 + h * DF + c] =
        bf16_of(W[(size_t)m * 16384 + c * DF + h]);
  } else if (i < 4 * 4 * 16384 + 4 * 4096) {
    int j = i - 4 * 4 * 16384;
    web[j] = bf16_of(We[j]);  // [conv][c][h]
  } else if (i < 4 * 4 * 16384 + 2 * 4 * 4096) {
    int j = i - (4 * 4 * 16384 + 4 * 4096);
    int conv = j >> 12, rr = j & 4095;
    int h = rr >> 5, c = rr & 31;
    webT[j] = bf16_of(We[(size_t)conv * 4096 + c * DF + h]);  // [conv][h][c]
  }
}

// ---------------- CSR build (both edge types fused) ----------------

__global__ void hist2_kernel(const int* __restrict__ d0, const int* __restrict__ d1,
                             int* __restrict__ cnt, int ne) {
  int i = blockIdx.x * blockDim.x + threadIdx.x;
  if (i < 2 * ne) {
    int t = (i >= ne);
    int e = i - t * ne;
    const int* d = t ? d1 : d0;
    atomicAdd(&cnt[t * (NNODE + 1) + d[e]], 1);
  }
}

// ---- 3-phase multi-block exclusive scan of cnt -> off ----

__global__ __launch_bounds__(1024) void scan_sum_kernel(const int* __restrict__ cntg,
                                                        int* __restrict__ bsum, int n) {
  __shared__ int lds[1024];
  int ty = blockIdx.y;
  const int* cnt = cntg + ty * (NNODE + 1);
  int t = threadIdx.x;
  int base = blockIdx.x * SCHUNK;
  int s = 0;
#pragma unroll
  for (int i = 0; i < 8; ++i) {
    int idx = base + t * 8 + i;
    s += (idx < n) ? cnt[idx] : 0;
  }
  lds[t] = s;
  __syncthreads();
#pragma unroll
  for (int st = 512; st > 0; st >>= 1) {
    if (t < st) lds[t] += lds[t + st];
    __syncthreads();
  }
  if (t == 0) bsum[ty * SBLK + blockIdx.x] = lds[0];
}

__global__ void scan_top_kernel(const int* __restrict__ bsum, int* __restrict__ bbase,
                                int* __restrict__ offg, int n) {
  int t = threadIdx.x;
  if (t < 2) {
    int s = 0;
    for (int i = 0; i < SBLK; ++i) {
      bbase[t * SBLK + i] = s;
      s += bsum[t * SBLK + i];
    }
    offg[t * (NNODE + 1) + n] = s;  // total
  }
}

__global__ __launch_bounds__(1024) void scan_local_kernel(const int* __restrict__ cntg,
                                                          const int* __restrict__ bbase,
                                                          int* __restrict__ offg, int n) {
  __shared__ int lds[1024];
  int ty = blockIdx.y;
  const int* cnt = cntg + ty * (NNODE + 1);
  int* off = offg + ty * (NNODE + 1);
  int t = threadIdx.x;
  int base = blockIdx.x * SCHUNK;
  int x[8];
  int s = 0;
#pragma unroll
  for (int i = 0; i < 8; ++i) {
    int idx = base + t * 8 + i;
    x[i] = (idx < n) ? cnt[idx] : 0;
    s += x[i];
  }
  lds[t] = s;
  __syncthreads();
#pragma unroll
  for (int st = 1; st < 1024; st <<= 1) {
    int v2 = (t >= st) ? lds[t - st] : 0;
    __syncthreads();
    lds[t] += v2;
    __syncthreads();
  }
  int excl = bbase[ty * SBLK + blockIdx.x] + lds[t] - s;
#pragma unroll
  for (int i = 0; i < 8; ++i) {
    int idx = base + t * 8 + i;
    if (idx < n) off[idx] = excl;
    excl += x[i];
  }
}

// init per-bucket global cursors from off
__global__ void initcur_kernel(const int* __restrict__ off, int* __restrict__ gcur) {
  int i = blockIdx.x * blockDim.x + threadIdx.x;
  if (i < 2 * NBUCK) {
    int t = (i >= NBUCK);
    int b = i - t * NBUCK;
    gcur[i] = off[t * (NNODE + 1) + b * NPB];
  }
}

// Pass A: bin edges into bucket-major tmp (packed 8B: e<<34 | d<<17 | s)
__global__ __launch_bounds__(256) void binA_kernel(
    const int* __restrict__ s0, const int* __restrict__ d0,
    const int* __restrict__ s1, const int* __restrict__ d1,
    int* __restrict__ gcur, long long* __restrict__ tmp0, long long* __restrict__ tmp1,
    int ne) {
  __shared__ int counts[NBUCK];
  __shared__ int gbase[NBUCK];
  int ty = blockIdx.y;
  const int* ss = ty ? s1 : s0;
  const int* dd = ty ? d1 : d0;
  long long* tmp = ty ? tmp1 : tmp0;
  int t = threadIdx.x;
  for (int i = t; i < NBUCK; i += 256) counts[i] = 0;
  __syncthreads();
  int e0 = blockIdx.x * EPB;
  int bb[8], lp[8], sv[8], dv[8];
#pragma unroll
  for (int i = 0; i < 8; ++i) {
    int e = e0 + i * 256 + t;
    if (e < ne) {
      int d = dd[e];
      sv[i] = ss[e];
      dv[i] = d;
      bb[i] = d >> NPB_SHIFT;
      lp[i] = atomicAdd(&counts[bb[i]], 1);
    } else {
      bb[i] = 0; lp[i] = 0; sv[i] = 0; dv[i] = 0;
    }
  }
  __syncthreads();
  for (int i = t; i < NBUCK; i += 256)
    gbase[i] = counts[i] ? atomicAdd(&gcur[ty * NBUCK + i], counts[i]) : 0;
  __syncthreads();
#pragma unroll
  for (int i = 0; i < 8; ++i) {
    int e = e0 + i * 256 + t;
    if (e < ne) {
      long long rec = ((long long)e << 34) | ((long long)dv[i] << 17) | (unsigned int)sv[i];
      tmp[gbase[bb[i]] + lp[i]] = rec;
    }
  }
}

// Pass B: within-bucket node scatter; writes confined to the bucket's CSR range
__global__ __launch_bounds__(256) void scatB_kernel(
    const long long* __restrict__ tmp0, const long long* __restrict__ tmp1,
    const int* __restrict__ off,
    long long* __restrict__ pair0, long long* __restrict__ pair1) {
  __shared__ int cur[NPB];
  int ty = blockIdx.y;
  const long long* tmp = ty ? tmp1 : tmp0;
  long long* pair = ty ? pair1 : pair0;
  const int* offT = off + ty * (NNODE + 1);
  int b = blockIdx.x;
  int n0 = b * NPB;
  int n1 = (n0 + NPB < NNODE) ? n0 + NPB : NNODE;
  int t = threadIdx.x;
  for (int i = t; i < n1 - n0; i += 256) cur[i] = offT[n0 + i];
  __syncthreads();
  int r0 = offT[n0], r1 = offT[n1];
  for (int j = r0 + t; j < r1; j += 256) {
    long long rec = tmp[j];
    int s = (int)(rec & 0x1FFFF);
    int d = (int)((rec >> 17) & 0x1FFFF);
    int e = (int)(rec >> 34);
    int p = atomicAdd(&cur[d - n0], 1);
    pair[p] = (unsigned int)s | ((long long)e << 32);
  }
}

// gather-permute: random line-exact ea reads, coalesced bf16 eac writes
__global__ __launch_bounds__(256) void permute_ea_kernel(
    const float* __restrict__ ea0, const long long* __restrict__ pair0,
    u16* __restrict__ eac0,
    const float* __restrict__ ea1, const long long* __restrict__ pair1,
    u16* __restrict__ eac1, int ne) {
  int gid = blockIdx.x * 256 + threadIdx.x;  // 4 threads per CSR slot
  int tot = ne * 4;
  if (gid >= 2 * tot) return;
  int ty = (gid >= tot);
  int g = gid - ty * tot;
  int j = g >> 2, part = g & 3;
  const long long* pair = ty ? pair1 : pair0;
  const float* ea = ty ? ea1 : ea0;
  u16* eac = ty ? eac1 : eac0;
  int e = (int)(pair[j] >> 32);
  const float4* r = (const float4*)(ea + (size_t)e * EDIM + part * 8);
  float4 a = r[0], b = r[1];
  short8v s;
  s[0] = bf16_of(a.x); s[1] = bf16_of(a.y); s[2] = bf16_of(a.z); s[3] = bf16_of(a.w);
  s[4] = bf16_of(b.x); s[5] = bf16_of(b.y); s[6] = bf16_of(b.z); s[7] = bf16_of(b.w);
  *(short8v*)(eac + (size_t)j * EDIM + part * 8) = s;
}

// ---------------- fused MFMA projections: q(+gq),k,v in one dispatch ----------------
// job0: q GEMM then gq = web @ q via LDS-staged q tile; job1: k,v into kvb rows of 256
__global__ __launch_bounds__(256) void proj_kernel(
    const short* __restrict__ xd, const short* __restrict__ xs, int n,
    const short* __restrict__ wtq, const float* __restrict__ bq, short* __restrict__ qb,
    const short* __restrict__ wtk, const float* __restrict__ bk,
    const short* __restrict__ wtv, const float* __restrict__ bv, short* __restrict__ kvb,
    const short* __restrict__ web, float* __restrict__ gq) {
  __shared__ short Xs[128 * 128];
  int t = threadIdx.x;
  int row0 = blockIdx.x * 128;
  int job = blockIdx.y;
  const short* X = job ? xs : xd;

#pragma unroll
  for (int i = 0; i < 8; ++i) {
    int idx8 = t + i * 256;
    int row = idx8 >> 4;
    int q8 = idx8 & 15;
    short8v val = (short8v){0, 0, 0, 0, 0, 0, 0, 0};
    if (row0 + row < n) val = ((const short8v*)(X + (size_t)(row0 + row) * DF))[q8];
    *(short8v*)&Xs[row * 128 + ((q8 ^ (row & 15)) << 3)] = val;
  }
  __syncthreads();

  int lane = t & 63, wave = t >> 6;
  int wm = wave >> 1, wh = wave & 1;
  int fr = lane & 15, kq = lane >> 4;
  int pmax = job ? 2 : 1;

  for (int p = 0; p < pmax; ++p) {
    const short* Wt = job ? (p ? wtv : wtk) : wtq;
    const float* bb = job ? (p ? bv : bk) : bq;
    f32x4 acc[4][4];
#pragma unroll
    for (int m = 0; m < 4; ++m)
#pragma unroll
      for (int nf = 0; nf < 4; ++nf) acc[m][nf] = (f32x4){0.f, 0.f, 0.f, 0.f};

#pragma unroll
    for (int kk = 0; kk < 4; ++kk) {
      short8v xf[4], wf[4];
      int chunk = kk * 4 + kq;
#pragma unroll
      for (int m = 0; m < 4; ++m) {
        int row = wm * 64 + m * 16 + fr;
        xf[m] = *(const short8v*)&Xs[row * 128 + ((chunk ^ (row & 15)) << 3)];
      }
#pragma unroll
      for (int nf = 0; nf < 4; ++nf) {
        int h = wh * 64 + nf * 16 + fr;
        wf[nf] = *(const short8v*)(Wt + (size_t)h * DF + kk * 32 + kq * 8);
      }
#pragma unroll
      for (int m = 0; m < 4; ++m)
#pragma unroll
        for (int nf = 0; nf < 4; ++nf)
          acc[m][nf] = __builtin_amdgcn_mfma_f32_16x16x32_bf16(wf[nf], xf[m], acc[m][nf], 0, 0, 0);
    }

    if (!job) __syncthreads();  // all waves done reading Xs before q-tile overwrite

#pragma unroll
    for (int nf = 0; nf < 4; ++nf) {
      float4 b4 = *(const float4*)(bb + wh * 64 + nf * 16 + kq * 4);
#pragma unroll
      for (int m = 0; m < 4; ++m) {
        int node = row0 + wm * 64 + m * 16 + fr;
        f32x4 r = acc[m][nf];
        int col = wh * 64 + nf * 16 + kq * 4;
        short4 s4;
        s4.x = bf16_of(r[0] + b4.x);
        s4.y = bf16_of(r[1] + b4.y);
        s4.z = bf16_of(r[2] + b4.z);
        s4.w = bf16_of(r[3] + b4.w);
        if (node < n) {
          if (job) {
            *(short4*)(kvb + (size_t)node * 256 + p * 128 + col) = s4;
          } else {
            *(short4*)(qb + (size_t)node * DF + col) = s4;
          }
        }
        if (!job) {
          // stage q tile in LDS (swizzled): row = local node, chunk = col>>3
          int lrow = wm * 64 + m * 16 + fr;
          int chunk = col >> 3, within = col & 7;
          *(short4*)&Xs[lrow * 128 + ((chunk ^ (lrow & 15)) << 3) + within] = s4;
        }
      }
    }

    if (!job) {
      __syncthreads();
      // gq = web @ q : wave handles nodes wave*32..+32, all 32 c
      int nrow0 = wave * 32;
      f32x4 gacc[2][2];
#pragma unroll
      for (int mm = 0; mm < 2; ++mm)
#pragma unroll
        for (int nf = 0; nf < 2; ++nf) gacc[mm][nf] = (f32x4){0.f, 0.f, 0.f, 0.f};
#pragma unroll
      for (int kk = 0; kk < 4; ++kk) {
        short8v af[2], bfr[2];
#pragma unroll
        for (int nf = 0; nf < 2; ++nf) {
          int cc = nf * 16 + fr;
          af[nf] = *(const short8v*)(web + (size_t)cc * DF + kk * 32 + kq * 8);
        }
        int chunk = kk * 4 + kq;
#pragma unroll
        for (int mm = 0; mm < 2; ++mm) {
          int lrow = nrow0 + mm * 16 + fr;
          bfr[mm] = *(const short8v*)&Xs[lrow * 128 + ((chunk ^ (lrow & 15)) << 3)];
        }
#pragma unroll
        for (int mm = 0; mm < 2; ++mm)
#pragma unroll
          for (int nf = 0; nf < 2; ++nf)
            gacc[mm][nf] = __builtin_amdgcn_mfma_f32_16x16x32_bf16(af[nf], bfr[mm], gacc[mm][nf], 0, 0, 0);
      }
#pragma unroll
      for (int mm = 0; mm < 2; ++mm) {
        int node = row0 + nrow0 + mm * 16 + fr;
        if (node < n) {
#pragma unroll
          for (int nf = 0; nf < 2; ++nf)
            *(f32x4*)(gq + (size_t)node * 32 + nf * 16 + kq * 4) = gacc[mm][nf];
        }
      }
    }
  }
}

// ---------------- fused edge attention: 1 node per 16-lane group, 4 edges/iter ----------------
// outputs: tmpob = (agg/ssum + be) bf16 [n,128]; accb = (sum w*ea)/ssum bf16 [n,32]
template <int PERM>
__global__ __launch_bounds__(256) void edge_attn_kernel(
    const short* __restrict__ qb, const short* __restrict__ kvb,
    const float* __restrict__ gq, const float* __restrict__ be,
    const long long* __restrict__ pairs, const int* __restrict__ off,
    const u16* __restrict__ eac, const float* __restrict__ ea,
    short* __restrict__ tmpob, short* __restrict__ accb, int nd) {
  int lane = threadIdx.x & 63;
  int grp = lane >> 4, sl = lane & 15;
  int node = blockIdx.x * 16 + (threadIdx.x >> 6) * 4 + grp;
  if (node >= nd) return;
  int e0 = off[node], e1 = off[node + 1];

  // lane owns dims sl*8..+8 of its group's node
  ushort8v qu = *(const ushort8v*)((const u16*)qb + (size_t)node * DF + sl * 8);
  float qd[8];
#pragma unroll
  for (int d = 0; d < 8; ++d) qd[d] = f_of_bf16(qu[d]);
  float bed[8];
  {
    float4 b0 = *(const float4*)(be + sl * 8);
    float4 b1 = *(const float4*)(be + sl * 8 + 4);
    bed[0] = b0.x; bed[1] = b0.y; bed[2] = b0.z; bed[3] = b0.w;
    bed[4] = b1.x; bed[5] = b1.y; bed[6] = b1.z; bed[7] = b1.w;
  }
  float pb = 0.f;
#pragma unroll
  for (int d = 0; d < 8; ++d) pb += qd[d] * bed[d];
#pragma unroll
  for (int o = 1; o <= 8; o <<= 1) pb += __shfl_xor(pb, o);

  float2 gq2 = *(const float2*)(gq + (size_t)node * 32 + sl * 2);

  const float scale = 0.08838834764831845f;  // 128^-0.5
  float m = -INFINITY, ssum = 0.f, an0 = 0.f, an1 = 0.f;
  float agg[8];
#pragma unroll
  for (int d = 0; d < 8; ++d) agg[d] = 0.f;

  for (int j0 = e0; j0 < e1; j0 += 4) {
    int jc[4], si[4];
    float eax[4], eay[4], p[4], a[4];
    ushort8v kv[4], vv[4];
#pragma unroll
    for (int i = 0; i < 4; ++i) {
      int j = j0 + i;
      jc[i] = (j < e1) ? j : e1 - 1;
    }
    long long pr[4];
#pragma unroll
    for (int i = 0; i < 4; ++i) pr[i] = pairs[jc[i]];
#pragma unroll
    for (int i = 0; i < 4; ++i) si[i] = (int)(unsigned int)pr[i];
#pragma unroll
    for (int i = 0; i < 4; ++i) {
      if (PERM) {
        ushort2 u = *(const ushort2*)(eac + (size_t)jc[i] * EDIM + sl * 2);
        eax[i] = f_of_bf16(u.x); eay[i] = f_of_bf16(u.y);
      } else {
        int e = (int)(pr[i] >> 32);
        float2 f = *(const float2*)(ea + (size_t)e * EDIM + sl * 2);
        eax[i] = f.x; eay[i] = f.y;
      }
    }
#pragma unroll
    for (int i = 0; i < 4; ++i) {
      const u16* kvp = (const u16*)kvb + (size_t)si[i] * 256 + sl * 8;
      kv[i] = *(const ushort8v*)kvp;
      vv[i] = *(const ushort8v*)(kvp + 128);
    }
#pragma unroll
    for (int i = 0; i < 4; ++i) {
      p[i] = eax[i] * gq2.x + eay[i] * gq2.y;
#pragma unroll
      for (int d = 0; d < 8; ++d) p[i] += qd[d] * f_of_bf16(kv[i][d]);
    }
#pragma unroll
    for (int o = 1; o <= 8; o <<= 1) {
#pragma unroll
      for (int i = 0; i < 4; ++i) p[i] += __shfl_xor(p[i], o);
    }
#pragma unroll
    for (int i = 0; i < 4; ++i)
      a[i] = (j0 + i < e1) ? (p[i] + pb) * scale : -INFINITY;
    float mn = fmaxf(fmaxf(m, fmaxf(a[0], a[1])), fmaxf(a[2], a[3]));
    if (mn > m) {  // group-uniform
      float f = __expf(m - mn);
      ssum *= f; an0 *= f; an1 *= f;
#pragma unroll
      for (int d = 0; d < 8; ++d) agg[d] *= f;
      m = mn;
    }
#pragma unroll
    for (int i = 0; i < 4; ++i) {
      float w = __expf(a[i] - m);  // 0 for invalid (a = -inf)
      ssum += w;
      an0 += w * eax[i];
      an1 += w * eay[i];
#pragma unroll
      for (int d = 0; d < 8; ++d) agg[d] += w * f_of_bf16(vv[i][d]);
    }
  }

  float inv = (ssum > 0.f) ? 1.f / ssum : 0.f;
  short2 a2;
  a2.x = bf16_of(an0 * inv);
  a2.y = bf16_of(an1 * inv);
  *(short2*)(accb + (size_t)node * 32 + sl * 2) = a2;
  short8v t8;
#pragma unroll
  for (int d = 0; d < 8; ++d)
    t8[d] = bf16_of((ssum > 0.f) ? agg[d] * inv + bed[d] : 0.f);
  *(short8v*)(tmpob + (size_t)node * DF + sl * 8) = t8;
}

// ---------------- fused epilogue: out = [relu](xd@Ws + bs + tmpob + accb @ We) ----------------
__global__ __launch_bounds__(256) void skip_accw_kernel(
    const short* __restrict__ xd, int n,
    const short* __restrict__ wts, const float* __restrict__ bs,
    const short* __restrict__ tmpob, const short* __restrict__ accb,
    const short* __restrict__ webT,
    float* __restrict__ outf, short* __restrict__ outb, int relu) {
  __shared__ short Xs[128 * 128];
  int t = threadIdx.x;
  int row0 = blockIdx.x * 128;

#pragma unroll
  for (int i = 0; i < 8; ++i) {
    int idx8 = t + i * 256;
    int row = idx8 >> 4;
    int q8 = idx8 & 15;
    short8v val = (short8v){0, 0, 0, 0, 0, 0, 0, 0};
    if (row0 + row < n) val = ((const short8v*)(xd + (size_t)(row0 + row) * DF))[q8];
    *(short8v*)&Xs[row * 128 + ((q8 ^ (row & 15)) << 3)] = val;
  }
  __syncthreads();

  int lane = t & 63, wave = t >> 6;
  int wm = wave >> 1, wh = wave & 1;
  int fr = lane & 15, kq = lane >> 4;

  f32x4 acc[4][4];
#pragma unroll
  for (int m = 0; m < 4; ++m)
#pragma unroll
    for (int nf = 0; nf < 4; ++nf) acc[m][nf] = (f32x4){0.f, 0.f, 0.f, 0.f};

  // skip GEMM: xd @ Ws (same fragment pattern as proj)
#pragma unroll
  for (int kk = 0; kk < 4; ++kk) {
    short8v xf[4], wf[4];
    int chunk = kk * 4 + kq;
#pragma unroll
    for (int m = 0; m < 4; ++m) {
      int row = wm * 64 + m * 16 + fr;
      xf[m] = *(const short8v*)&Xs[row * 128 + ((chunk ^ (row & 15)) << 3)];
    }
#pragma unroll
    for (int nf = 0; nf < 4; ++nf) {
      int h = wh * 64 + nf * 16 + fr;
      wf[nf] = *(const short8v*)(wts + (size_t)h * DF + kk * 32 + kq * 8);
    }
#pragma unroll
    for (int m = 0; m < 4; ++m)
#pragma unroll
      for (int nf = 0; nf < 4; ++nf)
        acc[m][nf] = __builtin_amdgcn_mfma_f32_16x16x32_bf16(wf[nf], xf[m], acc[m][nf], 0, 0, 0);
  }

  // ee GEMM: accb @ We^T fragments (K=32, one MFMA per (m,nf)), accumulated into acc
  {
    short8v af[4], bm[4];
#pragma unroll
    for (int nf = 0; nf < 4; ++nf) {
      int h = wh * 64 + nf * 16 + fr;
      af[nf] = *(const short8v*)(webT + (size_t)h * 32 + kq * 8);
    }
#pragma unroll
    for (int m = 0; m < 4; ++m) {
      int row = row0 + wm * 64 + m * 16 + fr;
      int rc = (row < n) ? row : n - 1;
      bm[m] = *(const short8v*)(accb + (size_t)rc * 32 + kq * 8);
    }
#pragma unroll
    for (int m = 0; m < 4; ++m)
#pragma unroll
      for (int nf = 0; nf < 4; ++nf)
        acc[m][nf] = __builtin_amdgcn_mfma_f32_16x16x32_bf16(af[nf], bm[m], acc[m][nf], 0, 0, 0);
  }

#pragma unroll
  for (int nf = 0; nf < 4; ++nf) {
    float4 b4 = *(const float4*)(bs + wh * 64 + nf * 16 + kq * 4);
#pragma unroll
    for (int m = 0; m < 4; ++m) {
      int node = row0 + wm * 64 + m * 16 + fr;
      if (node < n) {
        int col = wh * 64 + nf * 16 + kq * 4;
        size_t o = (size_t)node * DF + col;
        ushort4 tb = *(const ushort4*)((const u16*)tmpob + o);
        f32x4 r = acc[m][nf];
        float r0 = r[0] + b4.x + f_of_bf16(tb.x);
        float r1 = r[1] + b4.y + f_of_bf16(tb.y);
        float r2 = r[2] + b4.z + f_of_bf16(tb.z);
        float r3 = r[3] + b4.w + f_of_bf16(tb.w);
        if (relu) {
          r0 = fmaxf(r0, 0.f); r1 = fmaxf(r1, 0.f);
          r2 = fmaxf(r2, 0.f); r3 = fmaxf(r3, 0.f);
        }
        if (outf) *(float4*)(outf + o) = make_float4(r0, r1, r2, r3);
        if (outb) {
          short4 s4;
          s4.x = bf16_of(r0); s4.y = bf16_of(r1); s4.z = bf16_of(r2); s4.w = bf16_of(r3);
          *(short4*)(outb + o) = s4;
        }
      }
    }
  }
}

// ---------------- launch ----------------

extern "C" void kernel_launch(void* const* d_in, const int* in_sizes, int n_in,
                              void* d_out, int out_size, void* d_ws, size_t ws_size,
                              hipStream_t stream) {
  const float* x_user = (const float*)d_in[0];
  const float* x_item = (const float*)d_in[1];
  const float* ea_ui = (const float*)d_in[2];
  const float* ea_iu = (const float*)d_in[3];
  const float* Wq = (const float*)d_in[4];
  const float* bq = (const float*)d_in[5];
  const float* Wk = (const float*)d_in[6];
  const float* bk = (const float*)d_in[7];
  const float* Wv = (const float*)d_in[8];
  const float* bv = (const float*)d_in[9];
  const float* We = (const float*)d_in[10];
  const float* be = (const float*)d_in[11];
  const float* Ws = (const float*)d_in[12];
  const float* bs = (const float*)d_in[13];
  const int* ei_ui = (const int*)d_in[14];
  const int* ei_iu = (const int*)d_in[15];
  float* out = (float*)d_out;

  char* wp = (char*)d_ws;
  size_t used = 0;
  auto alloc = [&](size_t bytes) {
    void* p = (void*)(wp + used);
    used += (bytes + 255) & ~(size_t)255;
    return p;
  };
  const size_t NB = (size_t)NNODE * DF;
  short* xub = (short*)alloc(NB * 2);
  short* xib = (short*)alloc(NB * 2);
  short* xu1b = (short*)alloc(NB * 2);
  short* xi1b = (short*)alloc(NB * 2);
  short* qb = (short*)alloc(NB * 2);
  short* kvb = (short*)alloc(NB * 4);   // interleaved k|v rows of 256
  short* tmpob = (short*)alloc(NB * 2);
  float* gqbuf = (float*)alloc((size_t)NNODE * 32 * 4);
  short* accb = (short*)alloc((size_t)NNODE * 32 * 2);
  short* wt = (short*)alloc((size_t)4 * 4 * 16384 * 2);
  short* web = (short*)alloc((size_t)4 * 4096 * 2);
  short* webT = (short*)alloc((size_t)4 * 4096 * 2);
  int* cnt = (int*)alloc((size_t)2 * (NNODE + 1) * 4);
  int* off = (int*)alloc((size_t)2 * (NNODE + 1) * 4);
  int* bsum = (int*)alloc((size_t)2 * SBLK * 4);
  int* bbase = (int*)alloc((size_t)2 * SBLK * 4);
  int* gcur = (int*)alloc((size_t)2 * NBUCK * 4);
  long long* tmp_ui = (long long*)alloc((size_t)NEDGE * 8);
  long long* tmp_iu = (long long*)alloc((size_t)NEDGE * 8);
  long long* pair_ui = (long long*)alloc((size_t)NEDGE * 8);
  long long* pair_iu = (long long*)alloc((size_t)NEDGE * 8);
  size_t eac_bytes = (size_t)NEDGE * EDIM * 2;
  bool use_eac = (used + 2 * (eac_bytes + 256)) <= ws_size;
  u16* eac_ui = use_eac ? (u16*)alloc(eac_bytes) : nullptr;
  u16* eac_iu = use_eac ? (u16*)alloc(eac_bytes) : nullptr;

  const int PB = (NNODE + 127) / 128;  // 782
  int* off_ui = off;
  int* off_iu = off + (NNODE + 1);

  cast2_kernel<<<(int)(2 * NB / 4 + 255) / 256, 256, 0, stream>>>(
      x_user, x_item, xub, xib, (int)(NB / 4));
  transW_kernel<<<(4 * 4 * 16384 + 2 * 4 * 4096 + 255) / 256, 256, 0, stream>>>(
      Wq, Wk, Wv, Ws, We, wt, web, webT);

  hipMemsetAsync(cnt, 0, 2 * (NNODE + 1) * sizeof(int), stream);
  hist2_kernel<<<(2 * NEDGE + 255) / 256, 256, 0, stream>>>(
      ei_ui + NEDGE, ei_iu + NEDGE, cnt, NEDGE);
  {
    dim3 gs(SBLK, 2);
    scan_sum_kernel<<<gs, 1024, 0, stream>>>(cnt, bsum, NNODE);
    scan_top_kernel<<<1, 64, 0, stream>>>(bsum, bbase, off, NNODE);
    scan_local_kernel<<<gs, 1024, 0, stream>>>(cnt, bbase, off, NNODE);
  }
  initcur_kernel<<<(2 * NBUCK + 255) / 256, 256, 0, stream>>>(off, gcur);
  {
    dim3 gA((NEDGE + EPB - 1) / EPB, 2);
    binA_kernel<<<gA, 256, 0, stream>>>(
        ei_ui, ei_ui + NEDGE, ei_iu, ei_iu + NEDGE, gcur, tmp_ui, tmp_iu, NEDGE);
    dim3 gB(NBUCK, 2);
    scatB_kernel<<<gB, 256, 0, stream>>>(tmp_ui, tmp_iu, off, pair_ui, pair_iu);
  }
  if (use_eac)
    permute_ea_kernel<<<(2 * NEDGE * 4 + 255) / 256, 256, 0, stream>>>(
        ea_ui, pair_ui, eac_ui, ea_iu, pair_iu, eac_iu, NEDGE);

  auto run_conv = [&](const short* xsb, const short* xdb, int wsel, const u16* eac_t,
                      const float* ea_t, const long long* pair_t,
                      const int* off_t, float* outfp, short* outbp, int relu) {
    dim3 g(PB, 2);
    proj_kernel<<<g, 256, 0, stream>>>(
        xdb, xsb, NNODE,
        wt + (size_t)0 * 65536 + (size_t)wsel * 16384, bq + (size_t)wsel * DF, qb,
        wt + (size_t)1 * 65536 + (size_t)wsel * 16384, bk + (size_t)wsel * DF,
        wt + (size_t)2 * 65536 + (size_t)wsel * 16384, bv + (size_t)wsel * DF, kvb,
        web + (size_t)wsel * 4096, gqbuf);
    if (use_eac)
      edge_attn_kernel<1><<<(NNODE + 15) / 16, 256, 0, stream>>>(
          qb, kvb, gqbuf, be + (size_t)wsel * DF,
          pair_t, off_t, eac_t, nullptr, tmpob, accb, NNODE);
    else
      edge_attn_kernel<0><<<(NNODE + 15) / 16, 256, 0, stream>>>(
          qb, kvb, gqbuf, be + (size_t)wsel * DF,
          pair_t, off_t, nullptr, ea_t, tmpob, accb, NNODE);
    skip_accw_kernel<<<PB, 256, 0, stream>>>(
        xdb, NNODE, wt + (size_t)3 * 65536 + (size_t)wsel * 16384, bs + (size_t)wsel * DF,
        tmpob, accb, webT + (size_t)wsel * 4096, outfp, outbp, relu);
  };

  // layer 0 (ReLU): outputs bf16 only
  run_conv(xub, xib, 0, eac_ui, ea_ui, pair_ui, off_ui, nullptr, xi1b, 1);
  run_conv(xib, xub, 1, eac_iu, ea_iu, pair_iu, off_iu, nullptr, xu1b, 1);
  // layer 1 (no ReLU): f32 into d_out = [x_user | x_item]
  run_conv(xu1b, xi1b, 2, eac_ui, ea_ui, pair_ui, off_ui, out + NB, nullptr, 0);
  run_conv(xi1b, xu1b, 3, eac_iu, ea_iu, pair_iu, off_iu, out, nullptr, 0);
}